// Round 10
// baseline (181.264 us; speedup 1.0000x reference)
//
#include <hip/hip_runtime.h>
#include <hip/hip_cooperative_groups.h>
#include <math.h>

namespace cg = cooperative_groups;

#define EPS 1e-8f
constexpr int N = 8192;
constexpr int NBLOCKS = 1024;          // 4 blocks/CU co-resident (cooperative)
constexpr int ROWS_PER_TILE = 8;
constexpr int COLS_PER_TILE = 1024;    // 256 threads * 4 floats
constexpr int NSTRIPES = N / COLS_PER_TILE;                 // 8
constexpr int NTILES = (N / ROWS_PER_TILE) * NSTRIPES;      // 8192
constexpr int TILES_PER_BLOCK = NTILES / NBLOCKS;           // 8
constexpr float LPOS = 0.7310585786300049f;  // sigmoid(+1)
constexpr float LNEG = 0.2689414213699951f;  // sigmoid(-1)

// ---------------------------------------------------------------------------
// Single fused cooperative kernel.
// Phase 1 (match): each block computes match data for 8 rows (2 per wave).
//   Lane L owns h in {L,L+64,L+128,L+192}; computes p1[h],p2[h] redundantly
//   (Wp/bp L1-resident) + the row's props; wave-reduces 5 dots.
//   Writes m2[row], subj[row], rowpack[row] = {m1, obj, EPS/|obj|, 0}.
// grid.sync() (device-scope; cross-XCD visibility via agent fence).
// Phase 2 (outer): 8 tiles of 8 rows x 1024 cols per block (R7's measured-
//   best tiling, 50.25 us). t = bid + k*NBLOCKS: resident blocks sweep a
//   contiguous row band. Fast path: link=sigmoid(+/-1) const folded into
//   per-column qp/qm -> 1 select + 1 mul per element. Rare |t|<EPS exact.
//   Plain float4 stores (nt measured slower 62.9; tid*8 slower 54.8;
//   128-VGPR persistent prefetch slower 53.0).
// ---------------------------------------------------------------------------
__device__ __forceinline__ float exact_elem(float a, float oi, float m2c,
                                            float sjc) {
  const float t = oi * sjc;
  const float z = t / fmaxf(fabsf(t), EPS);
  return a * m2c * (1.f / (1.f + __expf(-z)));
}

__global__ __launch_bounds__(256, 4) void fused_kernel(
    const float* __restrict__ pat1, const float* __restrict__ pat2,
    const float* __restrict__ Wp, const float* __restrict__ bp,
    const float* __restrict__ wm, const float* __restrict__ Wq,
    const float* __restrict__ bq,
    float4* __restrict__ rowpack, float* __restrict__ m2arr,
    float* __restrict__ subjarr, float* __restrict__ out) {
  const int wid = threadIdx.x >> 6;
  const int lane = threadIdx.x & 63;

  // ---------------- Phase 1: match for rows bid*8 .. bid*8+7 ----------------
  {
    const float a0 = pat1[0], a1 = pat1[1], a2 = pat1[2];
    const float b0 = pat2[0], b1 = pat2[1], b2 = pat2[2];
#pragma unroll
    for (int rr = 0; rr < 2; ++rr) {
      const int row = blockIdx.x * 8 + rr * 4 + wid;
      const float x0 = wm[row * 3 + 0];
      const float x1 = wm[row * 3 + 1];
      const float x2 = wm[row * 3 + 2];
      float s0 = 0.f, s1 = 0.f, s2 = 0.f, n1 = 0.f, n2 = 0.f;
#pragma unroll
      for (int k = 0; k < 4; ++k) {
        const int h = lane + k * 64;
        const float wp0 = Wp[h * 3 + 0], wp1 = Wp[h * 3 + 1],
                    wp2 = Wp[h * 3 + 2];
        const float bph = bp[h];
        const float v1 = fmaf(wp0, a0, fmaf(wp1, a1, fmaf(wp2, a2, bph)));
        const float v2 = fmaf(wp0, b0, fmaf(wp1, b1, fmaf(wp2, b2, bph)));
        const float v  = fmaf(Wq[h * 3 + 0], x0,
                         fmaf(Wq[h * 3 + 1], x1,
                         fmaf(Wq[h * 3 + 2], x2, bq[h])));
        s0 = fmaf(v, v, s0);
        s1 = fmaf(v, v1, s1);
        s2 = fmaf(v, v2, s2);
        n1 = fmaf(v1, v1, n1);
        n2 = fmaf(v2, v2, n2);
      }
#pragma unroll
      for (int off = 32; off > 0; off >>= 1) {
        s0 += __shfl_xor(s0, off, 64);
        s1 += __shfl_xor(s1, off, 64);
        s2 += __shfl_xor(s2, off, 64);
        n1 += __shfl_xor(n1, off, 64);
        n2 += __shfl_xor(n2, off, 64);
      }
      if (lane == 0) {
        const float pn = sqrtf(s0);
        const float d1 = fmaxf(pn * sqrtf(n1), EPS);
        const float d2 = fmaxf(pn * sqrtf(n2), EPS);
        const float mm1 = 1.f / (1.f + __expf(-(s1 / d1)));
        const float mm2 = 1.f / (1.f + __expf(-(s2 / d2)));
        m2arr[row]   = mm2;
        subjarr[row] = x0;
        float4 rp;
        rp.x = mm1;                 // m1[i]
        rp.y = x2;                  // obj[i]
        rp.z = EPS / fabsf(x2);     // |subj_j| < thr <=> |t| < EPS
        rp.w = 0.f;
        rowpack[row] = rp;
      }
    }
  }

  __threadfence();            // device-scope release (cross-XCD visibility)
  cg::this_grid().sync();

  // ---------------- Phase 2: 8 outer tiles per block ----------------
#pragma unroll 1
  for (int k = 0; k < TILES_PER_BLOCK; ++k) {
    const int t = blockIdx.x + k * NBLOCKS;
    const int bx = t & (NSTRIPES - 1);
    const int by = t >> 3;
    const int jBase = bx * COLS_PER_TILE + (int)threadIdx.x * 4;
    const int iBase = by * ROWS_PER_TILE;
    const float4 m2v = *reinterpret_cast<const float4*>(m2arr + jBase);
    const float4 sjv = *reinterpret_cast<const float4*>(subjarr + jBase);
    float4 qp, qm, asj;
    qp.x = m2v.x * (sjv.x > 0.f ? LPOS : LNEG);
    qp.y = m2v.y * (sjv.y > 0.f ? LPOS : LNEG);
    qp.z = m2v.z * (sjv.z > 0.f ? LPOS : LNEG);
    qp.w = m2v.w * (sjv.w > 0.f ? LPOS : LNEG);
    qm.x = m2v.x * (sjv.x > 0.f ? LNEG : LPOS);
    qm.y = m2v.y * (sjv.y > 0.f ? LNEG : LPOS);
    qm.z = m2v.z * (sjv.z > 0.f ? LNEG : LPOS);
    qm.w = m2v.w * (sjv.w > 0.f ? LNEG : LPOS);
    asj.x = fabsf(sjv.x);
    asj.y = fabsf(sjv.y);
    asj.z = fabsf(sjv.z);
    asj.w = fabsf(sjv.w);
    const float minasj = fminf(fminf(asj.x, asj.y), fminf(asj.z, asj.w));
    const bool diagTile = (iBase >> 10) == bx;
#pragma unroll
    for (int r = 0; r < ROWS_PER_TILE; ++r) {
      const int i = iBase + r;
      const float4 rp = rowpack[i];   // block-uniform -> scalar load
      const float a = rp.x, oi = rp.y, thr = rp.z;
      const bool neg = oi < 0.f;
      float4 o;
      o.x = a * (neg ? qm.x : qp.x);
      o.y = a * (neg ? qm.y : qp.y);
      o.z = a * (neg ? qm.z : qp.z);
      o.w = a * (neg ? qm.w : qp.w);
      if (__builtin_expect(__any(minasj < thr), 0)) {
        if (asj.x < thr) o.x = exact_elem(a, oi, m2v.x, sjv.x);
        if (asj.y < thr) o.y = exact_elem(a, oi, m2v.y, sjv.y);
        if (asj.z < thr) o.z = exact_elem(a, oi, m2v.z, sjv.z);
        if (asj.w < thr) o.w = exact_elem(a, oi, m2v.w, sjv.w);
      }
      if (diagTile) {
        if (jBase + 0 == i) o.x = 0.f;
        if (jBase + 1 == i) o.y = 0.f;
        if (jBase + 2 == i) o.z = 0.f;
        if (jBase + 3 == i) o.w = 0.f;
      }
      *reinterpret_cast<float4*>(out + (size_t)i * N + jBase) = o;
    }
  }
}

// ---------------------------------------------------------------------------
extern "C" void kernel_launch(void* const* d_in, const int* in_sizes, int n_in,
                              void* d_out, int out_size, void* d_ws,
                              size_t ws_size, hipStream_t stream) {
  const float* pat1 = (const float*)d_in[0];
  const float* pat2 = (const float*)d_in[1];
  const float* wm   = (const float*)d_in[2];
  const float* Wp   = (const float*)d_in[3];
  const float* bp   = (const float*)d_in[4];
  const float* Wq   = (const float*)d_in[5];
  const float* bq   = (const float*)d_in[6];
  float* out = (float*)d_out;

  // ws layout: rowpack (N float4), m2 (N floats), subj (N floats)
  float4* rowpack = (float4*)d_ws;
  float* m2   = (float*)(rowpack + N);
  float* subj = m2 + N;

  void* args[] = {&pat1, &pat2, &Wp, &bp, &wm, &Wq, &bq,
                  &rowpack, &m2, &subj, &out};
  hipLaunchCooperativeKernel(reinterpret_cast<const void*>(&fused_kernel),
                             dim3(NBLOCKS), dim3(256), args, 0, stream);
}

// Round 11
// 50.180 us; speedup vs baseline: 3.6123x; 3.6123x over previous
//
#include <hip/hip_runtime.h>
#include <math.h>

#define EPS 1e-8f
constexpr int N = 8192;
constexpr int ROWS_PER_BLOCK = 8;
constexpr int COLS_PER_BLOCK = 1024;   // 256 threads * 4 floats
constexpr float LPOS = 0.7310585786300049f;  // sigmoid(+1)
constexpr float LNEG = 0.2689414213699951f;  // sigmoid(-1)

// ---------------------------------------------------------------------------
// Fused match kernel: one wave per row. Lane L owns h in {L,L+64,L+128,L+192};
// computes p1[h],p2[h] redundantly (Wp/bp L1-resident) + its row's props,
// wave-reduces 5 dots: |props|^2, props.p1, props.p2, |p1|^2, |p2|^2.
// Writes: m2[row], subj[row], rowpack[row] = {m1, obj, EPS/|obj|, 0}.
// ---------------------------------------------------------------------------
__global__ __launch_bounds__(256) void match_kernel(
    const float* __restrict__ pat1, const float* __restrict__ pat2,
    const float* __restrict__ Wp, const float* __restrict__ bp,
    const float* __restrict__ wm, const float* __restrict__ Wq,
    const float* __restrict__ bq,
    float4* __restrict__ rowpack, float* __restrict__ m2,
    float* __restrict__ subj) {
  const int row = (blockIdx.x * blockDim.x + threadIdx.x) >> 6;
  const int lane = threadIdx.x & 63;
  const float a0 = pat1[0], a1 = pat1[1], a2 = pat1[2];
  const float b0 = pat2[0], b1 = pat2[1], b2 = pat2[2];
  const float x0 = wm[row * 3 + 0];
  const float x1 = wm[row * 3 + 1];
  const float x2 = wm[row * 3 + 2];
  float s0 = 0.f, s1 = 0.f, s2 = 0.f, n1 = 0.f, n2 = 0.f;
#pragma unroll
  for (int k = 0; k < 4; ++k) {
    const int h = lane + k * 64;
    const float wp0 = Wp[h * 3 + 0], wp1 = Wp[h * 3 + 1], wp2 = Wp[h * 3 + 2];
    const float bph = bp[h];
    const float v1 = fmaf(wp0, a0, fmaf(wp1, a1, fmaf(wp2, a2, bph)));
    const float v2 = fmaf(wp0, b0, fmaf(wp1, b1, fmaf(wp2, b2, bph)));
    const float v  = fmaf(Wq[h * 3 + 0], x0,
                     fmaf(Wq[h * 3 + 1], x1,
                     fmaf(Wq[h * 3 + 2], x2, bq[h])));
    s0 = fmaf(v, v, s0);
    s1 = fmaf(v, v1, s1);
    s2 = fmaf(v, v2, s2);
    n1 = fmaf(v1, v1, n1);
    n2 = fmaf(v2, v2, n2);
  }
#pragma unroll
  for (int off = 32; off > 0; off >>= 1) {
    s0 += __shfl_xor(s0, off, 64);
    s1 += __shfl_xor(s1, off, 64);
    s2 += __shfl_xor(s2, off, 64);
    n1 += __shfl_xor(n1, off, 64);
    n2 += __shfl_xor(n2, off, 64);
  }
  if (lane == 0) {
    const float pn = sqrtf(s0);
    const float d1 = fmaxf(pn * sqrtf(n1), EPS);
    const float d2 = fmaxf(pn * sqrtf(n2), EPS);
    const float mm1 = 1.f / (1.f + __expf(-(s1 / d1)));
    const float mm2 = 1.f / (1.f + __expf(-(s2 / d2)));
    m2[row]   = mm2;
    subj[row] = x0;
    float4 rp;
    rp.x = mm1;                 // m1[i]
    rp.y = x2;                  // obj[i]
    rp.z = EPS / fabsf(x2);     // rare threshold: |subj_j| < thr <=> |t| < EPS
    rp.w = 0.f;
    rowpack[row] = rp;
  }
}

// ---------------------------------------------------------------------------
// Outer kernel, VALU-lean, block-churn (8192 light blocks). Measured-best
// configuration (50.25 us). out[i][j] = m1[i]*m2[j]*link(obj_i*subj_j),
// diag 0. link folded into per-column qp/qm (fast path: 1 select + 1 mul /
// element). Session evidence: nt stores slower (62.9); tid*8 stores slower
// (54.8, 32B-stride partial-line); persistent+prefetch slower (53.0, VGPR);
// row-per-block linear same (51.1); cooperative fusion much slower (181,
// per-XCD column-stripe channel hot-spotting).
// ---------------------------------------------------------------------------
__device__ __forceinline__ float exact_elem(float a, float oi, float m2c,
                                            float sjc) {
  const float t = oi * sjc;
  const float z = t / fmaxf(fabsf(t), EPS);
  return a * m2c * (1.f / (1.f + __expf(-z)));
}

__global__ __launch_bounds__(256) void outer_kernel(
    const float4* __restrict__ rowpack, const float* __restrict__ m2,
    const float* __restrict__ subj, float* __restrict__ out) {
  const int jBase = blockIdx.x * COLS_PER_BLOCK + threadIdx.x * 4;
  const int iBase = blockIdx.y * ROWS_PER_BLOCK;
  const float4 m2v = *reinterpret_cast<const float4*>(m2 + jBase);
  const float4 sjv = *reinterpret_cast<const float4*>(subj + jBase);
  float4 qp, qm, asj;
  qp.x = m2v.x * (sjv.x > 0.f ? LPOS : LNEG);
  qp.y = m2v.y * (sjv.y > 0.f ? LPOS : LNEG);
  qp.z = m2v.z * (sjv.z > 0.f ? LPOS : LNEG);
  qp.w = m2v.w * (sjv.w > 0.f ? LPOS : LNEG);
  qm.x = m2v.x * (sjv.x > 0.f ? LNEG : LPOS);
  qm.y = m2v.y * (sjv.y > 0.f ? LNEG : LPOS);
  qm.z = m2v.z * (sjv.z > 0.f ? LNEG : LPOS);
  qm.w = m2v.w * (sjv.w > 0.f ? LNEG : LPOS);
  asj.x = fabsf(sjv.x);
  asj.y = fabsf(sjv.y);
  asj.z = fabsf(sjv.z);
  asj.w = fabsf(sjv.w);
  const float minasj = fminf(fminf(asj.x, asj.y), fminf(asj.z, asj.w));
  const bool diagTile = (iBase >> 10) == (int)blockIdx.x;
#pragma unroll
  for (int r = 0; r < ROWS_PER_BLOCK; ++r) {
    const int i = iBase + r;
    const float4 rp = rowpack[i];   // block-uniform address -> scalar load
    const float a = rp.x, oi = rp.y, thr = rp.z;
    const bool neg = oi < 0.f;
    float4 o;
    o.x = a * (neg ? qm.x : qp.x);
    o.y = a * (neg ? qm.y : qp.y);
    o.z = a * (neg ? qm.z : qp.z);
    o.w = a * (neg ? qm.w : qp.w);
    if (__builtin_expect(__any(minasj < thr), 0)) {
      if (asj.x < thr) o.x = exact_elem(a, oi, m2v.x, sjv.x);
      if (asj.y < thr) o.y = exact_elem(a, oi, m2v.y, sjv.y);
      if (asj.z < thr) o.z = exact_elem(a, oi, m2v.z, sjv.z);
      if (asj.w < thr) o.w = exact_elem(a, oi, m2v.w, sjv.w);
    }
    if (diagTile) {
      if (jBase + 0 == i) o.x = 0.f;
      if (jBase + 1 == i) o.y = 0.f;
      if (jBase + 2 == i) o.z = 0.f;
      if (jBase + 3 == i) o.w = 0.f;
    }
    *reinterpret_cast<float4*>(out + (size_t)i * N + jBase) = o;
  }
}

// ---------------------------------------------------------------------------
extern "C" void kernel_launch(void* const* d_in, const int* in_sizes, int n_in,
                              void* d_out, int out_size, void* d_ws,
                              size_t ws_size, hipStream_t stream) {
  const float* pat1 = (const float*)d_in[0];
  const float* pat2 = (const float*)d_in[1];
  const float* wm   = (const float*)d_in[2];
  const float* Wp   = (const float*)d_in[3];
  const float* bp   = (const float*)d_in[4];
  const float* Wq   = (const float*)d_in[5];
  const float* bq   = (const float*)d_in[6];
  float* out = (float*)d_out;

  // ws layout: rowpack (N float4), m2 (N floats), subj (N floats)
  float4* rowpack = (float4*)d_ws;
  float* m2   = (float*)(rowpack + N);
  float* subj = m2 + N;

  match_kernel<<<N / 4, 256, 0, stream>>>(pat1, pat2, Wp, bp, wm, Wq, bq,
                                          rowpack, m2, subj);
  dim3 grid(N / COLS_PER_BLOCK, N / ROWS_PER_BLOCK);
  outer_kernel<<<grid, 256, 0, stream>>>(rowpack, m2, subj, out);
}